// Round 3
// baseline (174.644 us; speedup 1.0000x reference)
//
#include <hip/hip_runtime.h>

typedef unsigned short u16;
typedef __bf16   bf16x8 __attribute__((ext_vector_type(8)));
typedef float    f32x4  __attribute__((ext_vector_type(4)));
typedef unsigned u32x4v __attribute__((ext_vector_type(4)));
typedef u16      u16x8  __attribute__((ext_vector_type(8)));

#define DEV __device__ __forceinline__

DEV u16 f2bf(float f) {               // RNE f32 -> bf16
  unsigned u = __float_as_uint(f);
  u += 0x7fffu + ((u >> 16) & 1u);
  return (u16)(u >> 16);
}

DEV f32x4 fzero() { f32x4 z; z[0]=0.f; z[1]=0.f; z[2]=0.f; z[3]=0.f; return z; }

DEV void async_cp16(void* lds, const void* g) {
  __builtin_amdgcn_global_load_lds(
      (const __attribute__((address_space(1))) void*)g,
      (__attribute__((address_space(3))) void*)lds, 16, 0, 0);
}

// ---------------- f32 -> bf16 convert (n8 = count/8) ----------------
__global__ void k_cvt_bf16(const float* __restrict__ in, u16* __restrict__ out, int n8) {
  int i = blockIdx.x * blockDim.x + threadIdx.x;
  if (i >= n8) return;
  const float4* in4 = (const float4*)in;
  float4 a = in4[2*i], b = in4[2*i+1];
  u16x8 r;
  r[0]=f2bf(a.x); r[1]=f2bf(a.y); r[2]=f2bf(a.z); r[3]=f2bf(a.w);
  r[4]=f2bf(b.x); r[5]=f2bf(b.y); r[6]=f2bf(b.z); r[7]=f2bf(b.w);
  *(u16x8*)(out + 8*(size_t)i) = r;
}

// ---------------- mask == 0 detection ----------------
__global__ void k_zero_flag(unsigned* f) {
  if (threadIdx.x == 0 && blockIdx.x == 0) *f = 0u;
}

__global__ void k_mask_or(const u32x4v* __restrict__ m, int n4, unsigned* __restrict__ f) {
  unsigned o = 0;
  int stride = gridDim.x * blockDim.x;
  for (int i = blockIdx.x * blockDim.x + threadIdx.x; i < n4; i += stride) {
    u32x4v v = m[i];
    o |= v[0] | v[1] | v[2] | v[3];
  }
  if (o & 0x7fffffffu) atomicOr(f, 1u);   // ignore -0.0
}

// ---------------- NT GEMM: C[m,n] = sum_k A[m,k]*B[n,k], bf16 in, f32 acc ----
// 128x128 tile, BK=32, 4 waves, global_load_lds w/ source-side chunk swizzle.
// EPI 0: qkv epilogue (bias + scatter q,k row-major, v transposed)
// EPI 1: proj epilogue (bias + f32 out)
template<int EPI>
__global__ __launch_bounds__(256)
void k_gemm_nt(const u16* __restrict__ A, const u16* __restrict__ B,
               int N, int K, int nbn,
               const float* __restrict__ bq, const float* __restrict__ bk,
               const float* __restrict__ bv,
               u16* __restrict__ qo, u16* __restrict__ ko, u16* __restrict__ vto,
               float* __restrict__ fo, const float* __restrict__ bp)
{
  __shared__ u16 sA[2][4096];   // [128][32] bf16, chunk-swizzled
  __shared__ u16 sB[2][4096];

  const int tid  = threadIdx.x;
  const int lane = tid & 63;
  const int wave = tid >> 6;
  const int lr = lane & 15, lg = lane >> 4;
  const int wr = wave >> 1, wc = wave & 1;

  // XCD-aware swizzle (grid divisible by 8 for all our launches)
  const int per = gridDim.x >> 3;
  const int bid = blockIdx.x;
  const int swz = (bid & 7) * per + (bid >> 3);
  const int bm0 = (swz / nbn) << 7;
  const int bn0 = (swz - (swz / nbn) * nbn) << 7;

  const size_t Kb = (size_t)K * 2;   // row bytes

  auto stage = [&](int buf, int kt) {
#pragma unroll
    for (int j = 0; j < 2; ++j) {
      int off = (tid + j * 256) << 4;     // byte in 8KB tile
      int row = off >> 6;                 // 64B rows
      int ch  = (off & 63) >> 4;
      int gch = ch ^ (row & 3);           // involution
      async_cp16((char*)&sA[buf][0] + off,
                 (const char*)A + (size_t)(bm0 + row) * Kb + (size_t)kt * 64 + gch * 16);
      async_cp16((char*)&sB[buf][0] + off,
                 (const char*)B + (size_t)(bn0 + row) * Kb + (size_t)kt * 64 + gch * 16);
    }
  };

  f32x4 acc[4][4];
#pragma unroll
  for (int i = 0; i < 4; ++i)
#pragma unroll
    for (int j = 0; j < 4; ++j) acc[i][j] = fzero();

  const int nk = K >> 5;
  stage(0, 0);
  __syncthreads();

  for (int kt = 0; kt < nk; ++kt) {
    const int cur = kt & 1;
    if (kt + 1 < nk) stage(cur ^ 1, kt + 1);

    bf16x8 af[4], bfr[4];
#pragma unroll
    for (int mi = 0; mi < 4; ++mi) {
      int row = (wr << 6) + (mi << 4) + lr;
      int addr = (row << 6) + ((lg ^ (row & 3)) << 4);
      af[mi] = *(const bf16x8*)((const char*)&sA[cur][0] + addr);
    }
#pragma unroll
    for (int ni = 0; ni < 4; ++ni) {
      int row = (wc << 6) + (ni << 4) + lr;
      int addr = (row << 6) + ((lg ^ (row & 3)) << 4);
      bfr[ni] = *(const bf16x8*)((const char*)&sB[cur][0] + addr);
    }
#pragma unroll
    for (int mi = 0; mi < 4; ++mi)
#pragma unroll
      for (int ni = 0; ni < 4; ++ni)
        acc[mi][ni] = __builtin_amdgcn_mfma_f32_16x16x32_bf16(af[mi], bfr[ni], acc[mi][ni], 0, 0, 0);

    __syncthreads();
  }

  // epilogue: C row m = bm0 + wr*64 + mi*16 + lg*4 + r ; col = bn0 + wc*64 + ni*16 + lr
#pragma unroll
  for (int mi = 0; mi < 4; ++mi) {
#pragma unroll
    for (int ni = 0; ni < 4; ++ni) {
      int col = bn0 + (wc << 6) + (ni << 4) + lr;
      if (EPI == 0) {
        int s = col >> 10, hd = col & 1023;
        int h = hd >> 6, d = hd & 63;
        float bias = (s == 0 ? bq[hd] : (s == 1 ? bk[hd] : bv[hd]));
#pragma unroll
        for (int r = 0; r < 4; ++r) {
          int m = bm0 + (wr << 6) + (mi << 4) + (lg << 2) + r;
          int b = m >> 11, n = m & 2047;
          u16 val = f2bf(acc[mi][ni][r] + bias);
          size_t bh = (size_t)(b * 16 + h);
          if (s == 0)      qo[(bh * 2048 + n) * 64 + d] = val;
          else if (s == 1) ko[(bh * 2048 + n) * 64 + d] = val;
          else             vto[(bh * 64 + d) * 2048 + n] = val;  // V transposed
        }
      } else {
        float bias = bp[col];
#pragma unroll
        for (int r = 0; r < 4; ++r) {
          int m = bm0 + (wr << 6) + (mi << 4) + (lg << 2) + r;
          fo[(size_t)m * N + col] = acc[mi][ni][r] + bias;
        }
      }
    }
  }
}

// ---------------- flash attention ----------------
// grid = B*H*(N/64) = 1024 blocks, 256 threads (4 waves x 16 q-rows).
// Swapped QK^T: S^T = mfma(A=K, B=Q) -> lane (q = lane&15) owns its row's scores.
__global__ __launch_bounds__(256)
void k_attn(const u16* __restrict__ qb, const u16* __restrict__ kb,
            const u16* __restrict__ vtb, u16* __restrict__ ao,
            const float* __restrict__ mask, const unsigned* __restrict__ flag)
{
  constexpr int N = 2048, D = 64;
  __shared__ u16 sK[2][4096];   // [64 keys][64 d], chunk-swizzled rows (128B)
  __shared__ u16 sV[2][4096];   // [64 d][64 keys] (V^T), chunk-swizzled

  const int tid  = threadIdx.x;
  const int lane = tid & 63;
  const int wave = tid >> 6;
  const int lr = lane & 15, lg = lane >> 4;

  // XCD-aware mapping: each XCD sees 4 (b,h) pairs -> K/V stay L2-resident
  const int bid  = blockIdx.x;
  const int xcd  = bid & 7, slot = bid >> 3;
  const int bh   = xcd + 8 * (slot >> 5);
  const int qt   = slot & 31;
  const int b    = bh >> 4, h = bh & 15;

  const u16* Kbh = kb  + (size_t)bh * N * D;
  const u16* Vbh = vtb + (size_t)bh * D * N;
  const int q_lo = qt * 64 + wave * 16;
  const int qg   = q_lo + lr;          // this lane's q row

  bf16x8 qf[2];
  {
    const u16* qrow = qb + ((size_t)bh * N + qg) * D;
    qf[0] = *(const bf16x8*)(qrow + lg * 8);
    qf[1] = *(const bf16x8*)(qrow + 32 + lg * 8);
  }

  const unsigned use_mask = *flag;
  const float* maskb = mask + (size_t)b * N * N;

  float m_run = -INFINITY, lsum = 0.f;
  f32x4 o[4];
#pragma unroll
  for (int i = 0; i < 4; ++i) o[i] = fzero();

  auto stage = [&](int buf, int kt) {
#pragma unroll
    for (int j = 0; j < 2; ++j) {
      int off = (tid + j * 256) << 4;
      int row = off >> 7;               // 128B rows
      int ch  = (off & 127) >> 4;
      int gch = ch ^ (row & 7);
      async_cp16((char*)&sK[buf][0] + off,
                 (const char*)Kbh + (size_t)(kt * 64 + row) * 128 + gch * 16);
      async_cp16((char*)&sV[buf][0] + off,
                 (const char*)Vbh + (size_t)row * (N * 2) + (size_t)kt * 128 + gch * 16);
    }
  };

  stage(0, 0);
  __syncthreads();

  const float SCALE = 0.125f;   // hd^-0.5 (alpha cancels by shift-invariance)
  const float L2E   = 1.44269504088896340736f;

  for (int kt = 0; kt < N / 64; ++kt) {
    const int cur = kt & 1;
    if (kt + 1 < N / 64) stage(cur ^ 1, kt + 1);

    // S^T = K * Q^T : lane holds S[q=lr][key = mi*16 + lg*4 + r]
    f32x4 sc[4];
#pragma unroll
    for (int mi = 0; mi < 4; ++mi) sc[mi] = fzero();
#pragma unroll
    for (int mi = 0; mi < 4; ++mi)
#pragma unroll
      for (int ks = 0; ks < 2; ++ks) {
        int row = (mi << 4) + lr;
        int addr = (row << 7) + ((((ks << 2) + lg) ^ (row & 7)) << 4);
        bf16x8 kf = *(const bf16x8*)((const char*)&sK[cur][0] + addr);
        sc[mi] = __builtin_amdgcn_mfma_f32_16x16x32_bf16(kf, qf[ks], sc[mi], 0, 0, 0);
      }

    float t[4][4];
#pragma unroll
    for (int mi = 0; mi < 4; ++mi)
#pragma unroll
      for (int r = 0; r < 4; ++r) t[mi][r] = sc[mi][r] * SCALE;

    if (use_mask) {                      // slow path only if mask != 0
#pragma unroll
      for (int mi = 0; mi < 4; ++mi)
#pragma unroll
        for (int r = 0; r < 4; ++r) {
          int kg = kt * 64 + (mi << 4) + (lg << 2) + r;
          t[mi][r] += maskb[(size_t)qg * N + kg];
        }
    }

    // row max over 64 keys: 16 in-lane + xor16/xor32
    float pm = t[0][0];
#pragma unroll
    for (int mi = 0; mi < 4; ++mi)
#pragma unroll
      for (int r = 0; r < 4; ++r) pm = fmaxf(pm, t[mi][r]);
    pm = fmaxf(pm, __shfl_xor(pm, 16, 64));
    pm = fmaxf(pm, __shfl_xor(pm, 32, 64));

    const float m_new = fmaxf(m_run, pm);
    const float f = __builtin_amdgcn_exp2f((m_run - m_new) * L2E);
    m_run = m_new;

    float p[4][4];
    float rs = 0.f;
#pragma unroll
    for (int mi = 0; mi < 4; ++mi)
#pragma unroll
      for (int r = 0; r < 4; ++r) {
        p[mi][r] = __builtin_amdgcn_exp2f((t[mi][r] - m_new) * L2E);
        rs += p[mi][r];
      }
    rs += __shfl_xor(rs, 16, 64);
    rs += __shfl_xor(rs, 32, 64);
    lsum = lsum * f + rs;

    // rescale O (O rows = lg*4 + r; stats live at lane == row index)
    {
      float fr[4];
#pragma unroll
      for (int r = 0; r < 4; ++r) fr[r] = __shfl(f, (lg << 2) + r, 64);
#pragma unroll
      for (int ni = 0; ni < 4; ++ni)
#pragma unroll
        for (int r = 0; r < 4; ++r) o[ni][r] *= fr[r];
    }

    // pack P pairs: P32[mi][rp] = keys {mi*16 + lg*4 + 2rp, +1}
    unsigned P32[4][2];
#pragma unroll
    for (int mi = 0; mi < 4; ++mi)
#pragma unroll
      for (int rp = 0; rp < 2; ++rp) {
        unsigned lo = f2bf(p[mi][2 * rp]);
        unsigned hi = f2bf(p[mi][2 * rp + 1]);
        P32[mi][rp] = lo | (hi << 16);
      }

    // redistribute to PV A-frag: lane needs keys ks*32 + lg*8 + j
    bf16x8 pf[2];
#pragma unroll
    for (int ks = 0; ks < 2; ++ks) {
      u32x4v w;
#pragma unroll
      for (int wd = 0; wd < 4; ++wd) {
        int src = lr + ((((lg << 1) + (wd >> 1)) & 3) << 4);
        unsigned vlo = __shfl(P32[2 * ks + 0][wd & 1], src, 64);
        unsigned vhi = __shfl(P32[2 * ks + 1][wd & 1], src, 64);
        w[wd] = (lg & 2) ? vhi : vlo;
      }
      pf[ks] = __builtin_bit_cast(bf16x8, w);
    }

    // O += P * V (B-operand from V^T tile: contiguous ds_read_b128)
#pragma unroll
    for (int ni = 0; ni < 4; ++ni)
#pragma unroll
      for (int ks = 0; ks < 2; ++ks) {
        int drow = (ni << 4) + lr;
        int addr = (drow << 7) + ((((ks << 2) + lg) ^ (drow & 7)) << 4);
        bf16x8 vf = *(const bf16x8*)((const char*)&sV[cur][0] + addr);
        o[ni] = __builtin_amdgcn_mfma_f32_16x16x32_bf16(pf[ks], vf, o[ni], 0, 0, 0);
      }

    __syncthreads();
  }

  // normalize + store bf16 [b, n, h*64+d]
  const float inv = 1.0f / lsum;
  float ivr[4];
#pragma unroll
  for (int r = 0; r < 4; ++r) ivr[r] = __shfl(inv, (lg << 2) + r, 64);

#pragma unroll
  for (int ni = 0; ni < 4; ++ni) {
    int d = (ni << 4) + lr;
#pragma unroll
    for (int r = 0; r < 4; ++r) {
      int qrow = q_lo + (lg << 2) + r;
      ao[((size_t)(b * N + qrow)) * 1024 + h * 64 + d] = f2bf(o[ni][r] * ivr[r]);
    }
  }
}

// ---------------- launch ----------------
extern "C" void kernel_launch(void* const* d_in, const int* in_sizes, int n_in,
                              void* d_out, int out_size, void* d_ws, size_t ws_size,
                              hipStream_t stream) {
  const float* x      = (const float*)d_in[0];
  const float* mask   = (const float*)d_in[1];
  const float* w_qkv  = (const float*)d_in[2];
  const float* q_bias = (const float*)d_in[3];
  const float* k_bias = (const float*)d_in[4];
  const float* v_bias = (const float*)d_in[5];
  const float* w_proj = (const float*)d_in[6];
  const float* b_proj = (const float*)d_in[7];
  float* out = (float*)d_out;

  const int B = 2, N = 2048, C = 1024;
  const int M = B * N;                       // 4096

  // workspace layout (u16 units)
  u16* ws     = (u16*)d_ws;
  u16* xb     = ws;                          // 4096*1024        (x bf16; reused as attn_out)
  u16* wqkvb  = ws + 4194304;                // 3072*1024
  u16* wprojb = ws + 7340032;                // 1024*1024
  u16* qbuf   = ws + 8388608;                // 32*2048*64
  u16* kbuf   = ws + 12582912;
  u16* vtbuf  = ws + 16777216;               // [b,h,d,n]
  unsigned* flag = (unsigned*)(ws + 20971520);
  u16* aob    = xb;                          // reuse: x not needed after QKV GEMM

  k_cvt_bf16<<<(M * C / 8 + 255) / 256, 256, 0, stream>>>(x, xb, M * C / 8);
  k_cvt_bf16<<<(3 * C * C / 8 + 255) / 256, 256, 0, stream>>>(w_qkv, wqkvb, 3 * C * C / 8);
  k_cvt_bf16<<<(C * C / 8 + 255) / 256, 256, 0, stream>>>(w_proj, wprojb, C * C / 8);

  k_zero_flag<<<1, 64, 0, stream>>>(flag);
  k_mask_or<<<1024, 256, 0, stream>>>((const u32x4v*)mask, B * N * N / 4, flag);

  k_gemm_nt<0><<<(M / 128) * (3 * C / 128), 256, 0, stream>>>(
      xb, wqkvb, 3 * C, C, 3 * C / 128,
      q_bias, k_bias, v_bias, qbuf, kbuf, vtbuf, nullptr, nullptr);

  k_attn<<<B * 16 * (N / 64), 256, 0, stream>>>(qbuf, kbuf, vtbuf, aob, mask, flag);

  k_gemm_nt<1><<<(M / 128) * (C / 128), 256, 0, stream>>>(
      aob, wprojb, C, C, C / 128,
      nullptr, nullptr, nullptr, nullptr, nullptr, nullptr, out, b_proj);
}

// Round 4
// 159.498 us; speedup vs baseline: 1.0950x; 1.0950x over previous
//
#include <hip/hip_runtime.h>

typedef unsigned short u16;
typedef __bf16   bf16x8 __attribute__((ext_vector_type(8)));
typedef float    f32x4  __attribute__((ext_vector_type(4)));
typedef unsigned u32x4v __attribute__((ext_vector_type(4)));
typedef u16      u16x8  __attribute__((ext_vector_type(8)));

#define DEV __device__ __forceinline__

DEV u16 tobf(float f) {               // RNE via HW convert (m240: casts beat asm)
  return __builtin_bit_cast(unsigned short, (__bf16)f);
}

DEV unsigned pack2(float a, float b) { // 2xf32 -> packed 2xbf16 (compiler may fuse to v_cvt_pk)
  return (unsigned)tobf(a) | ((unsigned)tobf(b) << 16);
}

DEV f32x4 fzero() { f32x4 z; z[0]=0.f; z[1]=0.f; z[2]=0.f; z[3]=0.f; return z; }

DEV void async_cp16(void* lds, const void* g) {
  __builtin_amdgcn_global_load_lds(
      (const __attribute__((address_space(1))) void*)g,
      (__attribute__((address_space(3))) void*)lds, 16, 0, 0);
}

DEV void cvt8(const float* __restrict__ in, u16* __restrict__ out, int i) {
  const float4* in4 = (const float4*)in;
  float4 a = in4[2*i], b = in4[2*i+1];
  u16x8 r;
  r[0]=tobf(a.x); r[1]=tobf(a.y); r[2]=tobf(a.z); r[3]=tobf(a.w);
  r[4]=tobf(b.x); r[5]=tobf(b.y); r[6]=tobf(b.z); r[7]=tobf(b.w);
  *(u16x8*)(out + 8*(size_t)i) = r;
}

// ---------------- fused pre-pass: f32->bf16 converts + mask-nonzero OR -------
__global__ void k_zero_flag(unsigned* f) {
  if (threadIdx.x == 0 && blockIdx.x == 0) *f = 0u;
}

__global__ __launch_bounds__(256)
void k_pre(const float* __restrict__ x, const float* __restrict__ wqkv,
           const float* __restrict__ wproj,
           u16* __restrict__ xb, u16* __restrict__ wqkvb, u16* __restrict__ wprojb,
           const u32x4v* __restrict__ mask, unsigned* __restrict__ flag)
{
  const int tid = blockIdx.x * blockDim.x + threadIdx.x;
  const int stride = gridDim.x * blockDim.x;       // 524288 threads
  // x: 4M f32 = 524288 vec8 ; wqkv: 393216 ; wproj: 131072
  for (int i = tid; i < 524288; i += stride) cvt8(x, xb, i);
  for (int i = tid; i < 393216; i += stride) cvt8(wqkv, wqkvb, i);
  for (int i = tid; i < 131072; i += stride) cvt8(wproj, wprojb, i);
  unsigned o = 0;
  for (int i = tid; i < 2097152; i += stride) {    // B*N*N/4 u32x4
    u32x4v v = mask[i];
    o |= v[0] | v[1] | v[2] | v[3];
  }
  if (o & 0x7fffffffu) atomicOr(flag, 1u);         // ignore -0.0
}

// ---------------- NT GEMM: C[m,n] = sum_k A[m,k]*B[n,k], bf16 in, f32 acc ----
// 128x128 tile, BK=32, 4 waves, global_load_lds w/ source-side chunk swizzle.
// EPI 0: qkv epilogue (bias, q pre-scaled by 0.125, scatter q,k row-major, v transposed)
// EPI 1: proj epilogue (bias + f32 out)
template<int EPI>
__global__ __launch_bounds__(256)
void k_gemm_nt(const u16* __restrict__ A, const u16* __restrict__ B,
               int N, int K, int nbn,
               const float* __restrict__ bq, const float* __restrict__ bk,
               const float* __restrict__ bv,
               u16* __restrict__ qo, u16* __restrict__ ko, u16* __restrict__ vto,
               float* __restrict__ fo, const float* __restrict__ bp)
{
  __shared__ u16 sA[2][4096];   // [128][32] bf16, chunk-swizzled
  __shared__ u16 sB[2][4096];

  const int tid  = threadIdx.x;
  const int lane = tid & 63;
  const int wave = tid >> 6;
  const int lr = lane & 15, lg = lane >> 4;
  const int wr = wave >> 1, wc = wave & 1;

  const int per = gridDim.x >> 3;
  const int bid = blockIdx.x;
  const int swz = (bid & 7) * per + (bid >> 3);
  const int bm0 = (swz / nbn) << 7;
  const int bn0 = (swz - (swz / nbn) * nbn) << 7;

  const size_t Kb = (size_t)K * 2;

  auto stage = [&](int buf, int kt) {
#pragma unroll
    for (int j = 0; j < 2; ++j) {
      int off = (tid + j * 256) << 4;
      int row = off >> 6;
      int ch  = (off & 63) >> 4;
      int gch = ch ^ (row & 3);
      async_cp16((char*)&sA[buf][0] + off,
                 (const char*)A + (size_t)(bm0 + row) * Kb + (size_t)kt * 64 + gch * 16);
      async_cp16((char*)&sB[buf][0] + off,
                 (const char*)B + (size_t)(bn0 + row) * Kb + (size_t)kt * 64 + gch * 16);
    }
  };

  f32x4 acc[4][4];
#pragma unroll
  for (int i = 0; i < 4; ++i)
#pragma unroll
    for (int j = 0; j < 4; ++j) acc[i][j] = fzero();

  const int nk = K >> 5;
  stage(0, 0);
  __syncthreads();

  for (int kt = 0; kt < nk; ++kt) {
    const int cur = kt & 1;
    if (kt + 1 < nk) stage(cur ^ 1, kt + 1);

    bf16x8 af[4], bfr[4];
#pragma unroll
    for (int mi = 0; mi < 4; ++mi) {
      int row = (wr << 6) + (mi << 4) + lr;
      int addr = (row << 6) + ((lg ^ (row & 3)) << 4);
      af[mi] = *(const bf16x8*)((const char*)&sA[cur][0] + addr);
    }
#pragma unroll
    for (int ni = 0; ni < 4; ++ni) {
      int row = (wc << 6) + (ni << 4) + lr;
      int addr = (row << 6) + ((lg ^ (row & 3)) << 4);
      bfr[ni] = *(const bf16x8*)((const char*)&sB[cur][0] + addr);
    }
#pragma unroll
    for (int mi = 0; mi < 4; ++mi)
#pragma unroll
      for (int ni = 0; ni < 4; ++ni)
        acc[mi][ni] = __builtin_amdgcn_mfma_f32_16x16x32_bf16(af[mi], bfr[ni], acc[mi][ni], 0, 0, 0);

    __syncthreads();
  }

#pragma unroll
  for (int mi = 0; mi < 4; ++mi) {
#pragma unroll
    for (int ni = 0; ni < 4; ++ni) {
      int col = bn0 + (wc << 6) + (ni << 4) + lr;
      if (EPI == 0) {
        int s = col >> 10, hd = col & 1023;
        int h = hd >> 6, d = hd & 63;
        float bias = (s == 0 ? bq[hd] : (s == 1 ? bk[hd] : bv[hd]));
#pragma unroll
        for (int r = 0; r < 4; ++r) {
          int m = bm0 + (wr << 6) + (mi << 4) + (lg << 2) + r;
          int b = m >> 11, n = m & 2047;
          float v = acc[mi][ni][r] + bias;
          if (s == 0) v *= 0.125f;            // fold hd^-0.5 into Q (exact pow2)
          u16 val = tobf(v);
          size_t bh = (size_t)(b * 16 + h);
          if (s == 0)      qo[(bh * 2048 + n) * 64 + d] = val;
          else if (s == 1) ko[(bh * 2048 + n) * 64 + d] = val;
          else             vto[(bh * 64 + d) * 2048 + n] = val;  // V transposed
        }
      } else {
        float bias = bp[col];
#pragma unroll
        for (int r = 0; r < 4; ++r) {
          int m = bm0 + (wr << 6) + (mi << 4) + (lg << 2) + r;
          fo[(size_t)m * N + col] = acc[mi][ni][r] + bias;
        }
      }
    }
  }
}

// ---------------- flash attention ----------------
// grid = B*H*(N/64) = 1024 blocks, 256 threads (4 waves x 16 q-rows).
// Swapped QK^T: S^T = mfma(A=K, B=Q) -> lane (q = lane&15) owns its row's scores.
// Q pre-scaled by 0.125 at QKV epilogue; alpha trick cancels by shift-invariance.
__global__ __launch_bounds__(256)
void k_attn(const u16* __restrict__ qb, const u16* __restrict__ kb,
            const u16* __restrict__ vtb, u16* __restrict__ ao,
            const float* __restrict__ mask, const unsigned* __restrict__ flag)
{
  constexpr int N = 2048, D = 64;
  __shared__ u16 sK[2][4096];   // [64 keys][64 d], chunk-swizzled rows (128B)
  __shared__ u16 sV[2][4096];   // [64 d][64 keys] (V^T), chunk-swizzled

  const int tid  = threadIdx.x;
  const int lane = tid & 63;
  const int wave = tid >> 6;
  const int lr = lane & 15, lg = lane >> 4;

  const int bid  = blockIdx.x;
  const int xcd  = bid & 7, slot = bid >> 3;
  const int bh   = xcd + 8 * (slot >> 5);
  const int qt   = slot & 31;
  const int b    = bh >> 4, h = bh & 15;

  const u16* Kbh = kb  + (size_t)bh * N * D;
  const u16* Vbh = vtb + (size_t)bh * D * N;
  const int q_lo = qt * 64 + wave * 16;
  const int qg   = q_lo + lr;

  bf16x8 qf[2];
  {
    const u16* qrow = qb + ((size_t)bh * N + qg) * D;
    qf[0] = *(const bf16x8*)(qrow + lg * 8);
    qf[1] = *(const bf16x8*)(qrow + 32 + lg * 8);
  }

  const unsigned use_mask = *flag;
  const float* maskb = mask + (size_t)b * N * N;

  float m_run = -INFINITY, lsum = 0.f;
  f32x4 o[4];
#pragma unroll
  for (int i = 0; i < 4; ++i) o[i] = fzero();

  auto stage = [&](int buf, int kt) {
#pragma unroll
    for (int j = 0; j < 2; ++j) {
      int off = (tid + j * 256) << 4;
      int row = off >> 7;
      int ch  = (off & 127) >> 4;
      int gch = ch ^ (row & 7);
      async_cp16((char*)&sK[buf][0] + off,
                 (const char*)Kbh + (size_t)(kt * 64 + row) * 128 + gch * 16);
      async_cp16((char*)&sV[buf][0] + off,
                 (const char*)Vbh + (size_t)row * (N * 2) + (size_t)kt * 128 + gch * 16);
    }
  };

  stage(0, 0);
  __syncthreads();

  const float L2E = 1.44269504088896340736f;

  for (int kt = 0; kt < N / 64; ++kt) {
    const int cur = kt & 1;
    if (kt + 1 < N / 64) stage(cur ^ 1, kt + 1);

    // S^T = K * Q^T : lane holds S[q=lr][key = mi*16 + lg*4 + r] (already scaled)
    f32x4 sc[4];
#pragma unroll
    for (int mi = 0; mi < 4; ++mi) sc[mi] = fzero();
    __builtin_amdgcn_s_setprio(1);
#pragma unroll
    for (int mi = 0; mi < 4; ++mi)
#pragma unroll
      for (int ks = 0; ks < 2; ++ks) {
        int row = (mi << 4) + lr;
        int addr = (row << 7) + ((((ks << 2) + lg) ^ (row & 7)) << 4);
        bf16x8 kf = *(const bf16x8*)((const char*)&sK[cur][0] + addr);
        sc[mi] = __builtin_amdgcn_mfma_f32_16x16x32_bf16(kf, qf[ks], sc[mi], 0, 0, 0);
      }
    __builtin_amdgcn_s_setprio(0);

    if (use_mask) {                      // slow path only if mask != 0
#pragma unroll
      for (int mi = 0; mi < 4; ++mi)
#pragma unroll
        for (int r = 0; r < 4; ++r) {
          int kg = kt * 64 + (mi << 4) + (lg << 2) + r;
          sc[mi][r] += maskb[(size_t)qg * N + kg];
        }
    }

    // row max over 64 keys: 16 in-lane (tree) + xor16/xor32
    float a0 = fmaxf(fmaxf(sc[0][0], sc[0][1]), fmaxf(sc[0][2], sc[0][3]));
    float a1 = fmaxf(fmaxf(sc[1][0], sc[1][1]), fmaxf(sc[1][2], sc[1][3]));
    float a2 = fmaxf(fmaxf(sc[2][0], sc[2][1]), fmaxf(sc[2][2], sc[2][3]));
    float a3 = fmaxf(fmaxf(sc[3][0], sc[3][1]), fmaxf(sc[3][2], sc[3][3]));
    float pm = fmaxf(fmaxf(a0, a1), fmaxf(a2, a3));
    pm = fmaxf(pm, __shfl_xor(pm, 16, 64));
    pm = fmaxf(pm, __shfl_xor(pm, 32, 64));

    // defer-max (T13): only rescale when the running max grows past THR=8
    if (__any(pm > m_run + 8.f)) {
      const float m_new = fmaxf(m_run, pm);
      const float f = __builtin_amdgcn_exp2f((m_run - m_new) * L2E);
      m_run = m_new;
      float fr[4];
#pragma unroll
      for (int r = 0; r < 4; ++r) fr[r] = __shfl(f, (lg << 2) + r, 64);
#pragma unroll
      for (int ni = 0; ni < 4; ++ni)
#pragma unroll
        for (int r = 0; r < 4; ++r) o[ni][r] *= fr[r];
      lsum *= f;
    }

    const float mL2 = m_run * L2E;
    float p[4][4];
    float rs = 0.f;
#pragma unroll
    for (int mi = 0; mi < 4; ++mi)
#pragma unroll
      for (int r = 0; r < 4; ++r) {
        p[mi][r] = __builtin_amdgcn_exp2f(__builtin_fmaf(sc[mi][r], L2E, -mL2));
        rs += p[mi][r];
      }
    rs += __shfl_xor(rs, 16, 64);
    rs += __shfl_xor(rs, 32, 64);
    lsum += rs;

    // pack P pairs: P32[mi][rp] = keys {mi*16 + lg*4 + 2rp, +1}
    unsigned P32[4][2];
#pragma unroll
    for (int mi = 0; mi < 4; ++mi)
#pragma unroll
      for (int rp = 0; rp < 2; ++rp)
        P32[mi][rp] = pack2(p[mi][2 * rp], p[mi][2 * rp + 1]);

    // redistribute to PV A-frag: lane needs keys ks*32 + lg*8 + j
    bf16x8 pf[2];
#pragma unroll
    for (int ks = 0; ks < 2; ++ks) {
      u32x4v w;
#pragma unroll
      for (int wd = 0; wd < 4; ++wd) {
        int src = lr + ((((lg << 1) + (wd >> 1)) & 3) << 4);
        unsigned vlo = __shfl(P32[2 * ks + 0][wd & 1], src, 64);
        unsigned vhi = __shfl(P32[2 * ks + 1][wd & 1], src, 64);
        w[wd] = (lg & 2) ? vhi : vlo;
      }
      pf[ks] = __builtin_bit_cast(bf16x8, w);
    }

    // O += P * V (B-operand from V^T tile: contiguous ds_read_b128)
    __builtin_amdgcn_s_setprio(1);
#pragma unroll
    for (int ni = 0; ni < 4; ++ni)
#pragma unroll
      for (int ks = 0; ks < 2; ++ks) {
        int drow = (ni << 4) + lr;
        int addr = (drow << 7) + ((((ks << 2) + lg) ^ (drow & 7)) << 4);
        bf16x8 vf = *(const bf16x8*)((const char*)&sV[cur][0] + addr);
        o[ni] = __builtin_amdgcn_mfma_f32_16x16x32_bf16(pf[ks], vf, o[ni], 0, 0, 0);
      }
    __builtin_amdgcn_s_setprio(0);

    __syncthreads();
  }

  // normalize + store bf16 [b, n, h*64+d]
  const float inv = 1.0f / lsum;
  float ivr[4];
#pragma unroll
  for (int r = 0; r < 4; ++r) ivr[r] = __shfl(inv, (lg << 2) + r, 64);

#pragma unroll
  for (int ni = 0; ni < 4; ++ni) {
    int d = (ni << 4) + lr;
#pragma unroll
    for (int r = 0; r < 4; ++r) {
      int qrow = q_lo + (lg << 2) + r;
      ao[((size_t)(b * N + qrow)) * 1024 + h * 64 + d] = tobf(o[ni][r] * ivr[r]);
    }
  }
}

// ---------------- launch ----------------
extern "C" void kernel_launch(void* const* d_in, const int* in_sizes, int n_in,
                              void* d_out, int out_size, void* d_ws, size_t ws_size,
                              hipStream_t stream) {
  const float* x      = (const float*)d_in[0];
  const float* mask   = (const float*)d_in[1];
  const float* w_qkv  = (const float*)d_in[2];
  const float* q_bias = (const float*)d_in[3];
  const float* k_bias = (const float*)d_in[4];
  const float* v_bias = (const float*)d_in[5];
  const float* w_proj = (const float*)d_in[6];
  const float* b_proj = (const float*)d_in[7];
  float* out = (float*)d_out;

  const int B = 2, N = 2048, C = 1024;
  const int M = B * N;                       // 4096

  // workspace layout (u16 units)
  u16* ws     = (u16*)d_ws;
  u16* xb     = ws;                          // 4096*1024 (x bf16; reused as attn_out)
  u16* wqkvb  = ws + 4194304;                // 3072*1024
  u16* wprojb = ws + 7340032;                // 1024*1024
  u16* qbuf   = ws + 8388608;                // 32*2048*64
  u16* kbuf   = ws + 12582912;
  u16* vtbuf  = ws + 16777216;               // [b,h,d,n]
  unsigned* flag = (unsigned*)(ws + 20971520);
  u16* aob    = xb;                          // reuse: x dead after QKV GEMM

  k_zero_flag<<<1, 64, 0, stream>>>(flag);
  k_pre<<<2048, 256, 0, stream>>>(x, w_qkv, w_proj, xb, wqkvb, wprojb,
                                  (const u32x4v*)mask, flag);

  k_gemm_nt<0><<<(M / 128) * (3 * C / 128), 256, 0, stream>>>(
      xb, wqkvb, 3 * C, C, 3 * C / 128,
      q_bias, k_bias, v_bias, qbuf, kbuf, vtbuf, nullptr, nullptr);

  k_attn<<<B * 16 * (N / 64), 256, 0, stream>>>(qbuf, kbuf, vtbuf, aob, mask, flag);

  k_gemm_nt<1><<<(M / 128) * (C / 128), 256, 0, stream>>>(
      aob, wprojb, C, C, C / 128,
      nullptr, nullptr, nullptr, nullptr, nullptr, nullptr, out, b_proj);
}

// Round 5
// 143.095 us; speedup vs baseline: 1.2205x; 1.1146x over previous
//
#include <hip/hip_runtime.h>

typedef unsigned short u16;
typedef __bf16   bf16x8 __attribute__((ext_vector_type(8)));
typedef float    f32x4  __attribute__((ext_vector_type(4)));
typedef float    f32x16 __attribute__((ext_vector_type(16)));
typedef unsigned u32x4v __attribute__((ext_vector_type(4)));
typedef u16      u16x8  __attribute__((ext_vector_type(8)));

#define DEV __device__ __forceinline__

DEV u16 tobf(float f) {               // RNE via HW convert
  return __builtin_bit_cast(unsigned short, (__bf16)f);
}

DEV unsigned pack2(float a, float b) { // 2xf32 -> packed 2xbf16
  return (unsigned)tobf(a) | ((unsigned)tobf(b) << 16);
}

DEV f32x4 fzero() { f32x4 z; z[0]=0.f; z[1]=0.f; z[2]=0.f; z[3]=0.f; return z; }

DEV void async_cp16(void* lds, const void* g) {
  __builtin_amdgcn_global_load_lds(
      (const __attribute__((address_space(1))) void*)g,
      (__attribute__((address_space(3))) void*)lds, 16, 0, 0);
}

DEV void cvt8(const float* __restrict__ in, u16* __restrict__ out, int i) {
  const float4* in4 = (const float4*)in;
  float4 a = in4[2*i], b = in4[2*i+1];
  u16x8 r;
  r[0]=tobf(a.x); r[1]=tobf(a.y); r[2]=tobf(a.z); r[3]=tobf(a.w);
  r[4]=tobf(b.x); r[5]=tobf(b.y); r[6]=tobf(b.z); r[7]=tobf(b.w);
  *(u16x8*)(out + 8*(size_t)i) = r;
}

// ---------------- fused pre-pass: f32->bf16 converts + mask-nonzero OR -------
__global__ void k_zero_flag(unsigned* f) {
  if (threadIdx.x == 0 && blockIdx.x == 0) *f = 0u;
}

__global__ __launch_bounds__(256)
void k_pre(const float* __restrict__ x, const float* __restrict__ wqkv,
           const float* __restrict__ wproj,
           u16* __restrict__ xb, u16* __restrict__ wqkvb, u16* __restrict__ wprojb,
           const u32x4v* __restrict__ mask, unsigned* __restrict__ flag)
{
  const int tid = blockIdx.x * blockDim.x + threadIdx.x;
  const int stride = gridDim.x * blockDim.x;
  for (int i = tid; i < 524288; i += stride) cvt8(x, xb, i);
  for (int i = tid; i < 393216; i += stride) cvt8(wqkv, wqkvb, i);
  for (int i = tid; i < 131072; i += stride) cvt8(wproj, wprojb, i);
  unsigned o = 0;
  for (int i = tid; i < 2097152; i += stride) {
    u32x4v v = mask[i];
    o |= v[0] | v[1] | v[2] | v[3];
  }
  if (o & 0x7fffffffu) atomicOr(flag, 1u);         // ignore -0.0
}

// ---------------- NT GEMM: C[m,n] = sum_k A[m,k]*B[n,k], bf16 in, f32 acc ----
template<int EPI>
__global__ __launch_bounds__(256)
void k_gemm_nt(const u16* __restrict__ A, const u16* __restrict__ B,
               int N, int K, int nbn,
               const float* __restrict__ bq, const float* __restrict__ bk,
               const float* __restrict__ bv,
               u16* __restrict__ qo, u16* __restrict__ ko, u16* __restrict__ vto,
               float* __restrict__ fo, const float* __restrict__ bp)
{
  __shared__ u16 sA[2][4096];   // [128][32] bf16, chunk-swizzled
  __shared__ u16 sB[2][4096];

  const int tid  = threadIdx.x;
  const int lane = tid & 63;
  const int wave = tid >> 6;
  const int lr = lane & 15, lg = lane >> 4;
  const int wr = wave >> 1, wc = wave & 1;

  const int per = gridDim.x >> 3;
  const int bid = blockIdx.x;
  const int swz = (bid & 7) * per + (bid >> 3);
  const int bm0 = (swz / nbn) << 7;
  const int bn0 = (swz - (swz / nbn) * nbn) << 7;

  const size_t Kb = (size_t)K * 2;

  auto stage = [&](int buf, int kt) {
#pragma unroll
    for (int j = 0; j < 2; ++j) {
      int off = (tid + j * 256) << 4;
      int row = off >> 6;
      int ch  = (off & 63) >> 4;
      int gch = ch ^ (row & 3);
      async_cp16((char*)&sA[buf][0] + off,
                 (const char*)A + (size_t)(bm0 + row) * Kb + (size_t)kt * 64 + gch * 16);
      async_cp16((char*)&sB[buf][0] + off,
                 (const char*)B + (size_t)(bn0 + row) * Kb + (size_t)kt * 64 + gch * 16);
    }
  };

  f32x4 acc[4][4];
#pragma unroll
  for (int i = 0; i < 4; ++i)
#pragma unroll
    for (int j = 0; j < 4; ++j) acc[i][j] = fzero();

  const int nk = K >> 5;
  stage(0, 0);
  __syncthreads();

  for (int kt = 0; kt < nk; ++kt) {
    const int cur = kt & 1;
    if (kt + 1 < nk) stage(cur ^ 1, kt + 1);

    bf16x8 af[4], bfr[4];
#pragma unroll
    for (int mi = 0; mi < 4; ++mi) {
      int row = (wr << 6) + (mi << 4) + lr;
      int addr = (row << 6) + ((lg ^ (row & 3)) << 4);
      af[mi] = *(const bf16x8*)((const char*)&sA[cur][0] + addr);
    }
#pragma unroll
    for (int ni = 0; ni < 4; ++ni) {
      int row = (wc << 6) + (ni << 4) + lr;
      int addr = (row << 6) + ((lg ^ (row & 3)) << 4);
      bfr[ni] = *(const bf16x8*)((const char*)&sB[cur][0] + addr);
    }
#pragma unroll
    for (int mi = 0; mi < 4; ++mi)
#pragma unroll
      for (int ni = 0; ni < 4; ++ni)
        acc[mi][ni] = __builtin_amdgcn_mfma_f32_16x16x32_bf16(af[mi], bfr[ni], acc[mi][ni], 0, 0, 0);

    __syncthreads();
  }

#pragma unroll
  for (int mi = 0; mi < 4; ++mi) {
#pragma unroll
    for (int ni = 0; ni < 4; ++ni) {
      int col = bn0 + (wc << 6) + (ni << 4) + lr;
      if (EPI == 0) {
        int s = col >> 10, hd = col & 1023;
        int h = hd >> 6, d = hd & 63;
        float bias = (s == 0 ? bq[hd] : (s == 1 ? bk[hd] : bv[hd]));
#pragma unroll
        for (int r = 0; r < 4; ++r) {
          int m = bm0 + (wr << 6) + (mi << 4) + (lg << 2) + r;
          int b = m >> 11, n = m & 2047;
          float v = acc[mi][ni][r] + bias;
          if (s == 0) v *= 0.125f;            // fold hd^-0.5 into Q (exact pow2)
          u16 val = tobf(v);
          size_t bh = (size_t)(b * 16 + h);
          if (s == 0)      qo[(bh * 2048 + n) * 64 + d] = val;
          else if (s == 1) ko[(bh * 2048 + n) * 64 + d] = val;
          else             vto[(bh * 64 + d) * 2048 + n] = val;  // V transposed
        }
      } else {
        float bias = bp[col];
#pragma unroll
        for (int r = 0; r < 4; ++r) {
          int m = bm0 + (wr << 6) + (mi << 4) + (lg << 2) + r;
          fo[(size_t)m * N + col] = acc[mi][ni][r] + bias;
        }
      }
    }
  }
}

// ---------------- flash attention, 32x32 MFMA ----------------
// grid = B*H*(N/128) = 512 blocks, 256 threads (4 waves x 32 q-rows).
// Swapped QK^T: S^T = mfma_32x32x16(A=K, B=Q) -> lane owns q = lane&31,
// 32 scores in regs (row = (reg&3)+8*(reg>>2)+4*hi per 32-key block).
// P redistribution to PV A-frag is pure lane<->lane+32: v_permlane32_swap_b32.
__global__ __launch_bounds__(256)
void k_attn(const u16* __restrict__ qb, const u16* __restrict__ kb,
            const u16* __restrict__ vtb, u16* __restrict__ ao,
            const float* __restrict__ mask, const unsigned* __restrict__ flag)
{
  constexpr int N = 2048;
  __shared__ u16 sK[2][4096];   // [64 keys][64 d], 128B rows, chunk-swizzled
  __shared__ u16 sV[2][4096];   // [64 d][64 keys] (V^T), chunk-swizzled

  const int tid  = threadIdx.x;
  const int lane = tid & 63;
  const int wave = tid >> 6;
  const int l31  = lane & 31;   // q-row within wave / d-col within block
  const int hi   = lane >> 5;

  const int bid  = blockIdx.x;
  const int xcd  = bid & 7, slot = bid >> 3;
  const int bh   = xcd + 8 * (slot >> 4);      // 4 bh per XCD -> KV L2-resident
  const int qt   = slot & 15;
  const int b    = bh >> 4, h = bh & 15;

  const u16* Kbh = kb  + (size_t)bh * N * 64;
  const u16* Vbh = vtb + (size_t)bh * 64 * N;
  const int q_lo = qt * 128 + wave * 32;
  const int qg   = q_lo + l31;

  // Q B-frag: lane holds Q[q=l31][d = ks*16 + hi*8 + j]
  bf16x8 qf[4];
  {
    const u16* qrow = qb + ((size_t)bh * N + qg) * 64;
#pragma unroll
    for (int ks = 0; ks < 4; ++ks)
      qf[ks] = *(const bf16x8*)(qrow + ks * 16 + hi * 8);
  }

  const unsigned use_mask = *flag;
  const float* maskb = mask + (size_t)b * N * N;

  float m_run = -INFINITY, lsum = 0.f;
  f32x16 o0, o1;
#pragma unroll
  for (int r = 0; r < 16; ++r) { o0[r] = 0.f; o1[r] = 0.f; }

  auto stage = [&](int buf, int kt) {
#pragma unroll
    for (int j = 0; j < 2; ++j) {
      int off = (tid + j * 256) << 4;
      int row = off >> 7;
      int ch  = (off & 127) >> 4;
      int gch = ch ^ (row & 7);
      async_cp16((char*)&sK[buf][0] + off,
                 (const char*)Kbh + (size_t)(kt * 64 + row) * 128 + gch * 16);
      async_cp16((char*)&sV[buf][0] + off,
                 (const char*)Vbh + (size_t)row * (N * 2) + (size_t)kt * 128 + gch * 16);
    }
  };

  stage(0, 0);
  __syncthreads();

  const float L2E = 1.44269504088896340736f;

  for (int kt = 0; kt < N / 64; ++kt) {
    const int cur = kt & 1;
    if (kt + 1 < N / 64) stage(cur ^ 1, kt + 1);

    // S^T: 2 key-blocks of 32, 4 k-slices of d each
    f32x16 sc0, sc1;
#pragma unroll
    for (int r = 0; r < 16; ++r) { sc0[r] = 0.f; sc1[r] = 0.f; }

    __builtin_amdgcn_s_setprio(1);
#pragma unroll
    for (int ks = 0; ks < 4; ++ks) {
      int row0 = l31;
      int a0 = (row0 << 7) + ((((ks << 1) + hi) ^ (row0 & 7)) << 4);
      bf16x8 kf0 = *(const bf16x8*)((const char*)&sK[cur][0] + a0);
      sc0 = __builtin_amdgcn_mfma_f32_32x32x16_bf16(kf0, qf[ks], sc0, 0, 0, 0);
      int row1 = 32 + l31;
      int a1 = (row1 << 7) + ((((ks << 1) + hi) ^ (row1 & 7)) << 4);
      bf16x8 kf1 = *(const bf16x8*)((const char*)&sK[cur][0] + a1);
      sc1 = __builtin_amdgcn_mfma_f32_32x32x16_bf16(kf1, qf[ks], sc1, 0, 0, 0);
    }
    __builtin_amdgcn_s_setprio(0);

    if (use_mask) {                      // slow path only if mask != 0
#pragma unroll
      for (int r = 0; r < 16; ++r) {
        int krow = (r & 3) + 8 * (r >> 2) + 4 * hi;
        sc0[r] += maskb[(size_t)qg * N + kt * 64 + krow];
        sc1[r] += maskb[(size_t)qg * N + kt * 64 + 32 + krow];
      }
    }

    // row max over 64 keys: balanced in-lane tree + xor32
    float t[8];
#pragma unroll
    for (int r = 0; r < 8; ++r)
      t[r] = fmaxf(fmaxf(sc0[r], sc0[r + 8]), fmaxf(sc1[r], sc1[r + 8]));
#pragma unroll
    for (int r = 0; r < 4; ++r) t[r] = fmaxf(t[r], t[r + 4]);
    float pm = fmaxf(fmaxf(t[0], t[1]), fmaxf(t[2], t[3]));
    pm = fmaxf(pm, __shfl_xor(pm, 32, 64));

    // defer-max (T13): rescale only when running max grows past THR=8
    if (__any(pm > m_run + 8.f)) {
      const float m_new = fmaxf(m_run, pm);
      const float f = __builtin_amdgcn_exp2f((m_run - m_new) * L2E);
      m_run = m_new;
      float fr[16];
#pragma unroll
      for (int r = 0; r < 16; ++r)
        fr[r] = __shfl(f, (r & 3) + 8 * (r >> 2) + 4 * hi, 64);
#pragma unroll
      for (int r = 0; r < 16; ++r) { o0[r] *= fr[r]; o1[r] *= fr[r]; }
      lsum *= f;
    }

    // p = exp(s - m) in place; 4-way partial sums
    const float mL2 = m_run * L2E;
    float rs0 = 0.f, rs1 = 0.f, rs2 = 0.f, rs3 = 0.f;
#pragma unroll
    for (int r = 0; r < 16; r += 4) {
      sc0[r]   = __builtin_amdgcn_exp2f(__builtin_fmaf(sc0[r],   L2E, -mL2));
      sc0[r+1] = __builtin_amdgcn_exp2f(__builtin_fmaf(sc0[r+1], L2E, -mL2));
      sc0[r+2] = __builtin_amdgcn_exp2f(__builtin_fmaf(sc0[r+2], L2E, -mL2));
      sc0[r+3] = __builtin_amdgcn_exp2f(__builtin_fmaf(sc0[r+3], L2E, -mL2));
      sc1[r]   = __builtin_amdgcn_exp2f(__builtin_fmaf(sc1[r],   L2E, -mL2));
      sc1[r+1] = __builtin_amdgcn_exp2f(__builtin_fmaf(sc1[r+1], L2E, -mL2));
      sc1[r+2] = __builtin_amdgcn_exp2f(__builtin_fmaf(sc1[r+2], L2E, -mL2));
      sc1[r+3] = __builtin_amdgcn_exp2f(__builtin_fmaf(sc1[r+3], L2E, -mL2));
      rs0 += sc0[r]   + sc1[r];
      rs1 += sc0[r+1] + sc1[r+1];
      rs2 += sc0[r+2] + sc1[r+2];
      rs3 += sc0[r+3] + sc1[r+3];
    }
    float rs = (rs0 + rs1) + (rs2 + rs3);
    rs += __shfl_xor(rs, 32, 64);
    lsum += rs;

    // pack pairs: P32[kb][t] = keys {2t,2t+1} of row-map (kp_l = 4*(t>>1)+(t&1)+2*hi)
    unsigned P32_0[8], P32_1[8];
#pragma unroll
    for (int tt = 0; tt < 8; ++tt) {
      P32_0[tt] = pack2(sc0[2 * tt], sc0[2 * tt + 1]);
      P32_1[tt] = pack2(sc1[2 * tt], sc1[2 * tt + 1]);
    }

    // redistribute to PV A-frag via permlane32_swap:
    // pa[ks16] words: c0 = out0(sw(P[4b],P[4b+2])), c2 = out1; c1/c3 from (4b+1,4b+3)
    bf16x8 pa[4];
#pragma unroll
    for (int ks16 = 0; ks16 < 4; ++ks16) {
      const int b4 = (ks16 & 1) << 2;
      unsigned c0, c1, c2, c3;
      if (ks16 < 2) { c0 = P32_0[b4]; c2 = P32_0[b4+2]; c1 = P32_0[b4+1]; c3 = P32_0[b4+3]; }
      else          { c0 = P32_1[b4]; c2 = P32_1[b4+2]; c1 = P32_1[b4+1]; c3 = P32_1[b4+3]; }
      asm volatile("v_permlane32_swap_b32 %0, %1" : "+v"(c0), "+v"(c2));
      asm volatile("v_permlane32_swap_b32 %0, %1" : "+v"(c1), "+v"(c3));
      u32x4v w; w[0] = c0; w[1] = c1; w[2] = c2; w[3] = c3;
      pa[ks16] = __builtin_bit_cast(bf16x8, w);
    }

    // O += P * V : B-frag = V^T[d = dblk*32 + l31][k-run], 2 d-blocks x 4 k-slices
    __builtin_amdgcn_s_setprio(1);
#pragma unroll
    for (int ks16 = 0; ks16 < 4; ++ks16) {
      int row0 = l31;
      int a0 = (row0 << 7) + ((((ks16 << 1) + hi) ^ (row0 & 7)) << 4);
      bf16x8 vf0 = *(const bf16x8*)((const char*)&sV[cur][0] + a0);
      o0 = __builtin_amdgcn_mfma_f32_32x32x16_bf16(pa[ks16], vf0, o0, 0, 0, 0);
      int row1 = 32 + l31;
      int a1 = (row1 << 7) + ((((ks16 << 1) + hi) ^ (row1 & 7)) << 4);
      bf16x8 vf1 = *(const bf16x8*)((const char*)&sV[cur][0] + a1);
      o1 = __builtin_amdgcn_mfma_f32_32x32x16_bf16(pa[ks16], vf1, o1, 0, 0, 0);
    }
    __builtin_amdgcn_s_setprio(0);

    __syncthreads();
  }

  // normalize + store bf16 [b, n, h*64+d]; O row q = (r&3)+8*(r>>2)+4*hi, col d = dblk*32+l31
  const float inv = 1.0f / lsum;
  float ivr[16];
#pragma unroll
  for (int r = 0; r < 16; ++r)
    ivr[r] = __shfl(inv, (r & 3) + 8 * (r >> 2) + 4 * hi, 64);

#pragma unroll
  for (int r = 0; r < 16; ++r) {
    int qrow = q_lo + (r & 3) + 8 * (r >> 2) + 4 * hi;
    size_t base = ((size_t)(b * N + qrow)) * 1024 + h * 64;
    ao[base + l31]      = tobf(o0[r] * ivr[r]);
    ao[base + 32 + l31] = tobf(o1[r] * ivr[r]);
  }
}

// ---------------- launch ----------------
extern "C" void kernel_launch(void* const* d_in, const int* in_sizes, int n_in,
                              void* d_out, int out_size, void* d_ws, size_t ws_size,
                              hipStream_t stream) {
  const float* x      = (const float*)d_in[0];
  const float* mask   = (const float*)d_in[1];
  const float* w_qkv  = (const float*)d_in[2];
  const float* q_bias = (const float*)d_in[3];
  const float* k_bias = (const float*)d_in[4];
  const float* v_bias = (const float*)d_in[5];
  const float* w_proj = (const float*)d_in[6];
  const float* b_proj = (const float*)d_in[7];
  float* out = (float*)d_out;

  const int B = 2, N = 2048, C = 1024;
  const int M = B * N;                       // 4096

  // workspace layout (u16 units)
  u16* ws     = (u16*)d_ws;
  u16* xb     = ws;                          // 4096*1024 (x bf16; reused as attn_out)
  u16* wqkvb  = ws + 4194304;                // 3072*1024
  u16* wprojb = ws + 7340032;                // 1024*1024
  u16* qbuf   = ws + 8388608;                // 32*2048*64
  u16* kbuf   = ws + 12582912;
  u16* vtbuf  = ws + 16777216;               // [b,h,d,n]
  unsigned* flag = (unsigned*)(ws + 20971520);
  u16* aob    = xb;                          // reuse: x dead after QKV GEMM

  k_zero_flag<<<1, 64, 0, stream>>>(flag);
  k_pre<<<2048, 256, 0, stream>>>(x, w_qkv, w_proj, xb, wqkvb, wprojb,
                                  (const u32x4v*)mask, flag);

  k_gemm_nt<0><<<(M / 128) * (3 * C / 128), 256, 0, stream>>>(
      xb, wqkvb, 3 * C, C, 3 * C / 128,
      q_bias, k_bias, v_bias, qbuf, kbuf, vtbuf, nullptr, nullptr);

  k_attn<<<B * 16 * (N / 128), 256, 0, stream>>>(qbuf, kbuf, vtbuf, aob, mask, flag);

  k_gemm_nt<1><<<(M / 128) * (C / 128), 256, 0, stream>>>(
      aob, wprojb, C, C, C / 128,
      nullptr, nullptr, nullptr, nullptr, nullptr, nullptr, out, b_proj);
}